// Round 12
// baseline (847.510 us; speedup 1.0000x reference)
//
#include <hip/hip_runtime.h>
#include <hip/hip_bf16.h>
#include <math.h>

#define B_ 256
#define T_ 256
#define I_ 2048
#define H_ 128

#define BM 128
#define BK 32
#define NKT (I_ / BK)   // 64 K-tiles
#define NBUF 3

// ---- instrumentation: internal repeats to surface per-kernel counters ----
#define PROJ_REP 4
#define SCAN_REP 4

typedef __attribute__((ext_vector_type(8))) short bf16x8;
typedef __attribute__((ext_vector_type(4))) float f32x4;
typedef _Float16 half2v __attribute__((ext_vector_type(2)));

static __device__ inline short f2bf(float f) {
    __hip_bfloat16 h = __float2bfloat16(f);
    return *reinterpret_cast<short*>(&h);
}

static __device__ inline bf16x8 pack8(float4 a, float4 b) {
    bf16x8 r;
    r[0] = f2bf(a.x); r[1] = f2bf(a.y); r[2] = f2bf(a.z); r[3] = f2bf(a.w);
    r[4] = f2bf(b.x); r[5] = f2bf(b.y); r[6] = f2bf(b.z); r[7] = f2bf(b.w);
    return r;
}

// barrier that drains ONLY lgkm (DS) — leaves global prefetch in flight
#define LGKM_BARRIER() do {                                  \
    asm volatile("s_waitcnt lgkmcnt(0)" ::: "memory");       \
    __builtin_amdgcn_sched_barrier(0);                       \
    __builtin_amdgcn_s_barrier();                            \
} while (0)

// B-tile row swizzle (4 units of 16B per 64B row)
static __device__ inline int sB(int r) { return (r & 3) ^ ((r >> 2) & 3); }

// ---------------------------------------------------------------------------
// Pre-kernel: W_ih fp32 -> bf16 (L2-resident operand).
// ---------------------------------------------------------------------------
__global__ __launch_bounds__(256) void convW(
    const float* __restrict__ W, short* __restrict__ Wb)
{
    const int g = blockIdx.x * 256 + threadIdx.x;
    const float4 v0 = reinterpret_cast<const float4*>(W)[2 * g];
    const float4 v1 = reinterpret_cast<const float4*>(W)[2 * g + 1];
    reinterpret_cast<bf16x8*>(Wb)[g] = pack8(v0, v1);
}

// ---------------------------------------------------------------------------
// Kernel 1: R11's proj_v2 (counted-vmcnt 3-buf pipeline, bf16 B), body
// repeated PROJ_REP times (idempotent).
// ---------------------------------------------------------------------------
__global__ __launch_bounds__(256, 2) void proj_mfma(
    const float* __restrict__ x, const short* __restrict__ Wb,
    const float* __restrict__ bih, const float* __restrict__ bhh,
    float* __restrict__ xp)
{
    __shared__ __align__(16) float As[NBUF][BM * BK];   // 3 x 16 KB
    __shared__ __align__(16) short Bs[NBUF][H_ * BK];   // 3 x 8 KB

    const int tid  = threadIdx.x;
    const int lane = tid & 63;
    const int wid  = tid >> 6;
    const int wr   = wid >> 1;
    const int wc   = wid & 1;
    const long row0 = (long)blockIdx.x * BM;

    const int fr = lane & 15;
    const int fq = lane >> 4;

    float biasr[4];
    #pragma unroll
    for (int n = 0; n < 4; ++n) {
        const int col = wc * 64 + n * 16 + fr;
        biasr[n] = bih[col] + bhh[col];
    }

    const int srow  = lane >> 3;
    const int sunitA = (lane & 7) ^ srow;
    const int rb0 = wid * 32;
    const int bu = lane & 3;

    auto STAGE = [&](int tt, int buf) {
        const int kk = tt * BK;
        #pragma unroll
        for (int i = 0; i < 4; ++i) {
            const int rbase = rb0 + i * 8;
            const float* ga = x + (row0 + rbase + srow) * I_ + kk + sunitA * 4;
            __builtin_amdgcn_global_load_lds(
                (const __attribute__((address_space(1))) void*)ga,
                (__attribute__((address_space(3))) void*)&As[buf][rbase * BK], 16, 0, 0);
        }
        #pragma unroll
        for (int i = 0; i < 2; ++i) {
            const int brow = wid * 32 + i * 16 + (lane >> 2);
            const int bswz = bu ^ sB(brow);
            const short* gb = Wb + (long)brow * I_ + kk + bswz * 8;
            __builtin_amdgcn_global_load_lds(
                (const __attribute__((address_space(1))) void*)gb,
                (__attribute__((address_space(3))) void*)&Bs[buf][(wid * 128 + i * 64) * 8], 16, 0, 0);
        }
    };

    for (int rep = 0; rep < PROJ_REP; ++rep) {
        f32x4 acc[4][4];
        #pragma unroll
        for (int m = 0; m < 4; ++m)
            #pragma unroll
            for (int n = 0; n < 4; ++n)
                acc[m][n] = (f32x4){0.f, 0.f, 0.f, 0.f};

        STAGE(0, 0);
        STAGE(1, 1);

        for (int t = 0; t < NKT; ++t) {
            const int p = t % 3;
            if (t == NKT - 1) { asm volatile("s_waitcnt vmcnt(0)" ::: "memory"); }
            else              { asm volatile("s_waitcnt vmcnt(6)" ::: "memory"); }
            __builtin_amdgcn_sched_barrier(0);
            __builtin_amdgcn_s_barrier();
            __builtin_amdgcn_sched_barrier(0);

            bf16x8 af[4], bfr[4];
            #pragma unroll
            for (int f = 0; f < 4; ++f) {
                const int ra_ = wr * 64 + f * 16 + fr;
                const float4 a0 = *reinterpret_cast<const float4*>(
                    &As[p][ra_ * BK + (((fq * 2)     ^ (ra_ & 7)) * 4)]);
                const float4 a1 = *reinterpret_cast<const float4*>(
                    &As[p][ra_ * BK + (((fq * 2 + 1) ^ (ra_ & 7)) * 4)]);
                af[f] = pack8(a0, a1);
                const int rb_ = wc * 64 + f * 16 + fr;
                bfr[f] = *reinterpret_cast<const bf16x8*>(
                    &Bs[p][rb_ * 32 + ((fq ^ sB(rb_)) * 8)]);
            }
            #pragma unroll
            for (int m = 0; m < 4; ++m)
                #pragma unroll
                for (int n = 0; n < 4; ++n)
                    acc[m][n] = __builtin_amdgcn_mfma_f32_16x16x32_bf16(
                        af[m], bfr[n], acc[m][n], 0, 0, 0);

            __builtin_amdgcn_s_barrier();
            __builtin_amdgcn_sched_barrier(0);
            if (t + 2 < NKT) STAGE(t + 2, (t + 2) % 3);
        }

        #pragma unroll
        for (int n = 0; n < 4; ++n) {
            const int col = wc * 64 + n * 16 + fr;
            #pragma unroll
            for (int m = 0; m < 4; ++m) {
                const long rbase = row0 + wr * 64 + m * 16 + fq * 4;
                #pragma unroll
                for (int j = 0; j < 4; ++j)
                    xp[(rbase + j) * H_ + col] = acc[m][n][j] + biasr[n];
            }
        }
        __syncthreads();   // rep boundary: stores/LDS settled
    }
}

// ---------------------------------------------------------------------------
// Kernel 2: R9's PROVEN 4-wave scan (f16 dot2, shfl_xor k-combine, lgkm-only
// barrier), body repeated SCAN_REP times.
// ---------------------------------------------------------------------------
__global__ __launch_bounds__(256) void scan_kernel(
    const float* __restrict__ xp, const float* __restrict__ Whh,
    const float* __restrict__ Wfc, const float* __restrict__ bfc,
    float* __restrict__ out)
{
    __shared__ __align__(16) unsigned hpk[2][H_ / 2];   // 64 u32 = 128 f16, dbuf

    const int tid  = threadIdx.x;
    const int lane = tid & 63;
    const int w    = tid >> 6;
    const int j    = w * 32 + (lane & 31);
    const int g    = lane >> 5;
    const int b    = blockIdx.x;

    half2v Wh[32];
    {
        const float4* wp = reinterpret_cast<const float4*>(&Whh[(long)j * H_ + g * 64]);
        #pragma unroll
        for (int q = 0; q < 16; ++q) {
            const float4 wv = wp[q];
            half2v p0, p1;
            p0[0] = (_Float16)wv.x; p0[1] = (_Float16)wv.y;
            p1[0] = (_Float16)wv.z; p1[1] = (_Float16)wv.w;
            Wh[2 * q]     = p0;
            Wh[2 * q + 1] = p1;
        }
    }
    const float* xprow = xp + (long)b * T_ * H_ + j;

    for (int rep = 0; rep < SCAN_REP; ++rep) {
        __syncthreads();                        // prev rep's FC reads done
        if (tid < H_ / 2) hpk[0][tid] = 0u;

        float xa = xprow[0 * H_];
        float xb = xprow[1 * H_];
        float xc = xprow[2 * H_];
        float xd = xprow[3 * H_];
        __syncthreads();

        auto body = [&](int t, float xpv) {
            const uint4* hp = reinterpret_cast<const uint4*>(&hpk[t & 1][g * 32]);
            float a0 = 0.f, a1 = 0.f, a2 = 0.f, a3 = 0.f;
            #pragma unroll
            for (int q = 0; q < 8; ++q) {
                const uint4 u = hp[q];
                a0 = __builtin_amdgcn_fdot2(__builtin_bit_cast(half2v, u.x), Wh[4*q+0], a0, false);
                a1 = __builtin_amdgcn_fdot2(__builtin_bit_cast(half2v, u.y), Wh[4*q+1], a1, false);
                a2 = __builtin_amdgcn_fdot2(__builtin_bit_cast(half2v, u.z), Wh[4*q+2], a2, false);
                a3 = __builtin_amdgcn_fdot2(__builtin_bit_cast(half2v, u.w), Wh[4*q+3], a3, false);
            }
            float part = (a0 + a1) + (a2 + a3);
            part += __shfl_xor(part, 32);
            const float pre = part + xpv;
            const float e = __expf(2.f * pre);
            const float h = 1.f - 2.f / (e + 1.f);
            if (g == 0) {
                reinterpret_cast<unsigned short*>(&hpk[(t + 1) & 1][0])[j] =
                    __builtin_bit_cast(unsigned short, (_Float16)h);
            }
            LGKM_BARRIER();
        };

        for (int t = 0; t < T_; t += 4) {
            float xu;
            xu = xa; if (t + 4 < T_) xa = xprow[(long)(t + 4) * H_];
            body(t + 0, xu);
            xu = xb; if (t + 5 < T_) xb = xprow[(long)(t + 5) * H_];
            body(t + 1, xu);
            xu = xc; if (t + 6 < T_) xc = xprow[(long)(t + 6) * H_];
            body(t + 2, xu);
            xu = xd; if (t + 7 < T_) xd = xprow[(long)(t + 7) * H_];
            body(t + 3, xu);
        }

        if (w == 0) {
            const unsigned u = hpk[0][lane];    // pair h[2l], h[2l+1]
            const half2v hh = __builtin_bit_cast(half2v, u);
            float v = (float)hh[0] * Wfc[2 * lane] + (float)hh[1] * Wfc[2 * lane + 1];
            #pragma unroll
            for (int off = 32; off > 0; off >>= 1) v += __shfl_down(v, off);
            if (lane == 0) out[b] = v + bfc[0];
        }
    }
}

// ---------------------------------------------------------------------------
extern "C" void kernel_launch(void* const* d_in, const int* in_sizes, int n_in,
                              void* d_out, int out_size, void* d_ws, size_t ws_size,
                              hipStream_t stream)
{
    const float* x   = (const float*)d_in[0];
    const float* Wih = (const float*)d_in[1];
    const float* Whh = (const float*)d_in[2];
    const float* bih = (const float*)d_in[3];
    const float* bhh = (const float*)d_in[4];
    const float* Wfc = (const float*)d_in[5];
    const float* bfc = (const float*)d_in[6];
    float* out = (float*)d_out;
    float* xp  = (float*)d_ws;                       // 32 MB scratch
    short* Wb  = (short*)((char*)d_ws + (size_t)B_ * T_ * H_ * sizeof(float));  // bf16 W_ih

    convW<<<dim3((H_ * I_) / (256 * 8)), dim3(256), 0, stream>>>(Wih, Wb);
    proj_mfma<<<dim3((B_ * T_) / BM), dim3(256), 0, stream>>>(x, Wb, bih, bhh, xp);
    scan_kernel<<<dim3(B_), dim3(256), 0, stream>>>(xp, Whh, Wfc, bfc, out);
}

// Round 13
// 232.451 us; speedup vs baseline: 3.6460x; 3.6460x over previous
//
#include <hip/hip_runtime.h>
#include <hip/hip_bf16.h>
#include <math.h>

#define B_ 256
#define T_ 256
#define I_ 2048
#define H_ 128

#define BM 64
#define BK 64
#define NKT (I_ / BK)   // 32 K-tiles

typedef __attribute__((ext_vector_type(8))) short bf16x8;
typedef __attribute__((ext_vector_type(4))) float f32x4;
typedef _Float16 half2v __attribute__((ext_vector_type(2)));

static __device__ inline short f2bf(float f) {
    __hip_bfloat16 h = __float2bfloat16(f);
    return *reinterpret_cast<short*>(&h);
}

static __device__ inline bf16x8 pack8(float4 a, float4 b) {
    bf16x8 r;
    r[0] = f2bf(a.x); r[1] = f2bf(a.y); r[2] = f2bf(a.z); r[3] = f2bf(a.w);
    r[4] = f2bf(b.x); r[5] = f2bf(b.y); r[6] = f2bf(b.z); r[7] = f2bf(b.w);
    return r;
}

// barrier that drains ONLY lgkm (DS) — leaves global prefetch in flight
#define LGKM_BARRIER() do {                                  \
    asm volatile("s_waitcnt lgkmcnt(0)" ::: "memory");       \
    __builtin_amdgcn_sched_barrier(0);                       \
    __builtin_amdgcn_s_barrier();                            \
} while (0)

// ---------------------------------------------------------------------------
// Pre-kernel: W_ih fp32 -> bf16 (L2-resident B operand).
// ---------------------------------------------------------------------------
__global__ __launch_bounds__(256) void convW(
    const float* __restrict__ W, short* __restrict__ Wb)
{
    const int g = blockIdx.x * 256 + threadIdx.x;
    const float4 v0 = reinterpret_cast<const float4*>(W)[2 * g];
    const float4 v1 = reinterpret_cast<const float4*>(W)[2 * g + 1];
    reinterpret_cast<bf16x8*>(Wb)[g] = pack8(v0, v1);
}

// ---------------------------------------------------------------------------
// Kernel 1 v3: BM=64, BK=64 (256-B contiguous A chunks -> DRAM-burst
// friendly; the measured cold-pass limiter at BK=32 was 128-B chunks at
// 8 KB stride = ~50% DRAM efficiency). R5's PROVEN 2-buf + __syncthreads
// structure. B pre-converted to bf16 (L2-resident, no B-side cvt).
// A swizzle: 16B-unit ^ (row&15) over [64][64] fp32 rows (16 units/row).
// B swizzle: 16B-unit ^ (row&7)  over [128][64] bf16 rows (8 units/row).
// Both applied source-side at staging and read-side at frag build.
// 4 waves: wave w owns cols [32w, 32w+32); grid 1024 blocks, 2 blocks/CU.
// ---------------------------------------------------------------------------
__global__ __launch_bounds__(256, 2) void proj_mfma(
    const float* __restrict__ x, const short* __restrict__ Wb,
    const float* __restrict__ bih, const float* __restrict__ bhh,
    float* __restrict__ xp)
{
    __shared__ __align__(16) float As[2][BM * BK];   // 2 x 16 KB
    __shared__ __align__(16) short Bs[2][H_ * BK];   // 2 x 16 KB

    const int tid  = threadIdx.x;
    const int lane = tid & 63;
    const int wid  = tid >> 6;
    const long row0 = (long)blockIdx.x * BM;

    const int fr = lane & 15;
    const int fq = lane >> 4;

    // bias for this wave's two col-tiles
    float biasr[2];
    #pragma unroll
    for (int n = 0; n < 2; ++n) {
        const int col = wid * 32 + n * 16 + fr;
        biasr[n] = bih[col] + bhh[col];
    }

    // staging decode (per gl_lds instruction: 64 lanes x 16 B = 1 KB)
    // A: slot = (wid*4+i)*64 + lane; row = slot>>4; unit' = lane&15
    const int arow_l = lane >> 4;            // row offset within 4-row chunk
    // B: slot = (wid*4+i)*64 + lane; row = slot>>3; unit' = lane&7
    const int brow_l = lane >> 3;            // row offset within 8-row chunk

    auto STAGE = [&](int tt, int buf) {
        const int kk = tt * BK;
        #pragma unroll
        for (int i = 0; i < 4; ++i) {
            const int r = (wid * 4 + i) * 4 + arow_l;
            const int u = (lane & 15) ^ (r & 15);
            const float* ga = x + (row0 + r) * I_ + kk + u * 4;
            __builtin_amdgcn_global_load_lds(
                (const __attribute__((address_space(1))) void*)ga,
                (__attribute__((address_space(3))) void*)&As[buf][(wid * 4 + i) * 256],
                16, 0, 0);
        }
        #pragma unroll
        for (int i = 0; i < 4; ++i) {
            const int r = (wid * 4 + i) * 8 + brow_l;
            const int u = (lane & 7) ^ (r & 7);
            const short* gb = Wb + (long)r * I_ + kk + u * 8;
            __builtin_amdgcn_global_load_lds(
                (const __attribute__((address_space(1))) void*)gb,
                (__attribute__((address_space(3))) void*)&Bs[buf][(wid * 4 + i) * 512],
                16, 0, 0);
        }
    };

    f32x4 acc[4][2];
    #pragma unroll
    for (int m = 0; m < 4; ++m)
        #pragma unroll
        for (int n = 0; n < 2; ++n)
            acc[m][n] = (f32x4){0.f, 0.f, 0.f, 0.f};

    STAGE(0, 0);
    __syncthreads();

    int p = 0;
    for (int t = 0; t < NKT; ++t) {
        if (t + 1 < NKT) STAGE(t + 1, p ^ 1);   // in flight across this compute

        bf16x8 af[4][2], bfr[2][2];
        #pragma unroll
        for (int m = 0; m < 4; ++m) {
            const int R = m * 16 + fr;
            #pragma unroll
            for (int kk = 0; kk < 2; ++kk) {
                const int U0 = kk * 8 + fq * 2;
                const float4 a0 = *reinterpret_cast<const float4*>(
                    &As[p][R * 64 + ((U0 ^ (R & 15)) << 2)]);
                const float4 a1 = *reinterpret_cast<const float4*>(
                    &As[p][R * 64 + (((U0 + 1) ^ (R & 15)) << 2)]);
                af[m][kk] = pack8(a0, a1);
            }
        }
        #pragma unroll
        for (int n = 0; n < 2; ++n) {
            const int R = wid * 32 + n * 16 + fr;
            #pragma unroll
            for (int kk = 0; kk < 2; ++kk) {
                const int U = kk * 4 + fq;
                bfr[n][kk] = *reinterpret_cast<const bf16x8*>(
                    &Bs[p][R * 64 + ((U ^ (R & 7)) << 3)]);
            }
        }
        #pragma unroll
        for (int kk = 0; kk < 2; ++kk)
            #pragma unroll
            for (int m = 0; m < 4; ++m)
                #pragma unroll
                for (int n = 0; n < 2; ++n)
                    acc[m][n] = __builtin_amdgcn_mfma_f32_16x16x32_bf16(
                        af[m][kk], bfr[n][kk], acc[m][n], 0, 0, 0);

        __syncthreads();   // buf p reads done; buf p^1 staging drained
        p ^= 1;
    }

    // epilogue: bias + store (C layout: row=(lane>>4)*4+j, col=lane&15)
    #pragma unroll
    for (int n = 0; n < 2; ++n) {
        const int col = wid * 32 + n * 16 + fr;
        #pragma unroll
        for (int m = 0; m < 4; ++m) {
            const long rbase = row0 + m * 16 + fq * 4;
            #pragma unroll
            for (int j = 0; j < 4; ++j)
                xp[(rbase + j) * H_ + col] = acc[m][n][j] + biasr[n];
        }
    }
}

// ---------------------------------------------------------------------------
// Kernel 2 (FROZEN R9, measured ~65 us/pass): 4-wave scan, f16 packed h in
// LDS, v_dot2_f32_f16, shfl_xor(32) k-half combine, lgkm-only barrier,
// 4-deep xp prefetch.
// ---------------------------------------------------------------------------
__global__ __launch_bounds__(256) void scan_kernel(
    const float* __restrict__ xp, const float* __restrict__ Whh,
    const float* __restrict__ Wfc, const float* __restrict__ bfc,
    float* __restrict__ out)
{
    __shared__ __align__(16) unsigned hpk[2][H_ / 2];   // 64 u32 = 128 f16, dbuf

    const int tid  = threadIdx.x;
    const int lane = tid & 63;
    const int w    = tid >> 6;
    const int j    = w * 32 + (lane & 31);
    const int g    = lane >> 5;
    const int b    = blockIdx.x;

    half2v Wh[32];
    {
        const float4* wp = reinterpret_cast<const float4*>(&Whh[(long)j * H_ + g * 64]);
        #pragma unroll
        for (int q = 0; q < 16; ++q) {
            const float4 wv = wp[q];
            half2v p0, p1;
            p0[0] = (_Float16)wv.x; p0[1] = (_Float16)wv.y;
            p1[0] = (_Float16)wv.z; p1[1] = (_Float16)wv.w;
            Wh[2 * q]     = p0;
            Wh[2 * q + 1] = p1;
        }
    }
    if (tid < H_ / 2) hpk[0][tid] = 0u;

    const float* xprow = xp + (long)b * T_ * H_ + j;
    float xa = xprow[0 * H_];
    float xb = xprow[1 * H_];
    float xc = xprow[2 * H_];
    float xd = xprow[3 * H_];
    __syncthreads();

    auto body = [&](int t, float xpv) {
        const uint4* hp = reinterpret_cast<const uint4*>(&hpk[t & 1][g * 32]);
        float a0 = 0.f, a1 = 0.f, a2 = 0.f, a3 = 0.f;
        #pragma unroll
        for (int q = 0; q < 8; ++q) {
            const uint4 u = hp[q];
            a0 = __builtin_amdgcn_fdot2(__builtin_bit_cast(half2v, u.x), Wh[4*q+0], a0, false);
            a1 = __builtin_amdgcn_fdot2(__builtin_bit_cast(half2v, u.y), Wh[4*q+1], a1, false);
            a2 = __builtin_amdgcn_fdot2(__builtin_bit_cast(half2v, u.z), Wh[4*q+2], a2, false);
            a3 = __builtin_amdgcn_fdot2(__builtin_bit_cast(half2v, u.w), Wh[4*q+3], a3, false);
        }
        float part = (a0 + a1) + (a2 + a3);
        part += __shfl_xor(part, 32);
        const float pre = part + xpv;
        const float e = __expf(2.f * pre);      // tanh = 1 - 2/(e^{2x}+1)
        const float h = 1.f - 2.f / (e + 1.f);
        if (g == 0) {
            reinterpret_cast<unsigned short*>(&hpk[(t + 1) & 1][0])[j] =
                __builtin_bit_cast(unsigned short, (_Float16)h);
        }
        LGKM_BARRIER();
    };

    for (int t = 0; t < T_; t += 4) {
        float xu;
        xu = xa; if (t + 4 < T_) xa = xprow[(long)(t + 4) * H_];
        body(t + 0, xu);
        xu = xb; if (t + 5 < T_) xb = xprow[(long)(t + 5) * H_];
        body(t + 1, xu);
        xu = xc; if (t + 6 < T_) xc = xprow[(long)(t + 6) * H_];
        body(t + 2, xu);
        xu = xd; if (t + 7 < T_) xd = xprow[(long)(t + 7) * H_];
        body(t + 3, xu);
    }

    // final FC: h_T is in hpk[0] (t=255 wrote (255+1)&1 = 0)
    if (w == 0) {
        const unsigned u = hpk[0][lane];        // pair h[2l], h[2l+1]
        const half2v hh = __builtin_bit_cast(half2v, u);
        float v = (float)hh[0] * Wfc[2 * lane] + (float)hh[1] * Wfc[2 * lane + 1];
        #pragma unroll
        for (int off = 32; off > 0; off >>= 1) v += __shfl_down(v, off);
        if (lane == 0) out[b] = v + bfc[0];
    }
}

// ---------------------------------------------------------------------------
extern "C" void kernel_launch(void* const* d_in, const int* in_sizes, int n_in,
                              void* d_out, int out_size, void* d_ws, size_t ws_size,
                              hipStream_t stream)
{
    const float* x   = (const float*)d_in[0];
    const float* Wih = (const float*)d_in[1];
    const float* Whh = (const float*)d_in[2];
    const float* bih = (const float*)d_in[3];
    const float* bhh = (const float*)d_in[4];
    const float* Wfc = (const float*)d_in[5];
    const float* bfc = (const float*)d_in[6];
    float* out = (float*)d_out;
    float* xp  = (float*)d_ws;                       // 32 MB scratch
    short* Wb  = (short*)((char*)d_ws + (size_t)B_ * T_ * H_ * sizeof(float));  // bf16 W_ih

    convW<<<dim3((H_ * I_) / (256 * 8)), dim3(256), 0, stream>>>(Wih, Wb);
    proj_mfma<<<dim3((B_ * T_) / BM), dim3(256), 0, stream>>>(x, Wb, bih, bhh, xp);
    scan_kernel<<<dim3(B_), dim3(256), 0, stream>>>(xp, Whh, Wfc, bfc, out);
}

// Round 14
// 231.024 us; speedup vs baseline: 3.6685x; 1.0062x over previous
//
#include <hip/hip_runtime.h>
#include <hip/hip_bf16.h>
#include <math.h>

#define B_ 256
#define T_ 256
#define I_ 2048
#define H_ 128

#define BM 64
#define BK 64
#define NKT (I_ / BK)   // 32 K-tiles

typedef __attribute__((ext_vector_type(8))) short bf16x8;
typedef __attribute__((ext_vector_type(4))) float f32x4;
typedef _Float16 half2v __attribute__((ext_vector_type(2)));

static __device__ inline short f2bf(float f) {
    __hip_bfloat16 h = __float2bfloat16(f);
    return *reinterpret_cast<short*>(&h);
}

static __device__ inline bf16x8 pack8(float4 a, float4 b) {
    bf16x8 r;
    r[0] = f2bf(a.x); r[1] = f2bf(a.y); r[2] = f2bf(a.z); r[3] = f2bf(a.w);
    r[4] = f2bf(b.x); r[5] = f2bf(b.y); r[6] = f2bf(b.z); r[7] = f2bf(b.w);
    return r;
}

// barrier that drains ONLY lgkm (DS) — leaves global prefetch in flight
#define LGKM_BARRIER() do {                                  \
    asm volatile("s_waitcnt lgkmcnt(0)" ::: "memory");       \
    __builtin_amdgcn_sched_barrier(0);                       \
    __builtin_amdgcn_s_barrier();                            \
} while (0)

// ---------------------------------------------------------------------------
// Pre-kernel: W_ih fp32 -> bf16 (L2-resident B operand).
// ---------------------------------------------------------------------------
__global__ __launch_bounds__(256) void convW(
    const float* __restrict__ W, short* __restrict__ Wb)
{
    const int g = blockIdx.x * 256 + threadIdx.x;
    const float4 v0 = reinterpret_cast<const float4*>(W)[2 * g];
    const float4 v1 = reinterpret_cast<const float4*>(W)[2 * g + 1];
    reinterpret_cast<bf16x8*>(Wb)[g] = pack8(v0, v1);
}

// ---------------------------------------------------------------------------
// Kernel 1 v4: A-only LDS (32 KB -> 4 blocks/CU, 16 waves/CU TLP — the
// R12-measured stall was barrier drain at 2 blocks/CU). B fragments load
// DIRECTLY global->VGPR from L2-resident bf16 Wb, prefetched 1 K-step
// ahead (drain at the same barrier as A staging). BM=64, BK=64 (256-B
// burst chunks), 2-buf + __syncthreads (proven), both-sides XOR swizzle
// (mapping verified in R13 by exact absmax).
// 4 waves: wave w owns cols [32w, 32w+32); grid 1024 blocks.
// ---------------------------------------------------------------------------
__global__ __launch_bounds__(256, 4) void proj_mfma(
    const float* __restrict__ x, const short* __restrict__ Wb,
    const float* __restrict__ bih, const float* __restrict__ bhh,
    float* __restrict__ xp)
{
    __shared__ __align__(16) float As[2][BM * BK];   // 2 x 16 KB (A only)

    const int tid  = threadIdx.x;
    const int lane = tid & 63;
    const int wid  = tid >> 6;
    const long row0 = (long)blockIdx.x * BM;

    const int fr = lane & 15;
    const int fq = lane >> 4;

    // bias for this wave's two col-tiles
    float biasr[2];
    #pragma unroll
    for (int n = 0; n < 2; ++n) {
        const int col = wid * 32 + n * 16 + fr;
        biasr[n] = bih[col] + bhh[col];
    }

    // A staging decode: 4 gl_lds/wave, each 4 rows x 256 B
    const int arow_l = lane >> 4;            // row offset within 4-row chunk

    auto STAGE = [&](int tt, int buf) {
        const int kk = tt * BK;
        #pragma unroll
        for (int i = 0; i < 4; ++i) {
            const int r = (wid * 4 + i) * 4 + arow_l;
            const int u = (lane & 15) ^ (r & 15);
            const float* ga = x + (row0 + r) * I_ + kk + u * 4;
            __builtin_amdgcn_global_load_lds(
                (const __attribute__((address_space(1))) void*)ga,
                (__attribute__((address_space(3))) void*)&As[buf][(wid * 4 + i) * 256],
                16, 0, 0);
        }
    };

    auto LOADB = [&](int tt, bf16x8 bc[2][2]) {
        #pragma unroll
        for (int n = 0; n < 2; ++n) {
            const int R = wid * 32 + n * 16 + fr;
            #pragma unroll
            for (int kk = 0; kk < 2; ++kk)
                bc[n][kk] = *reinterpret_cast<const bf16x8*>(
                    Wb + (long)R * I_ + tt * BK + kk * 32 + fq * 8);
        }
    };

    f32x4 acc[4][2];
    #pragma unroll
    for (int m = 0; m < 4; ++m)
        #pragma unroll
        for (int n = 0; n < 2; ++n)
            acc[m][n] = (f32x4){0.f, 0.f, 0.f, 0.f};

    bf16x8 bcA[2][2], bcB[2][2];

    // prologue: A tile 0 staged, B tile 0 in regs
    STAGE(0, 0);
    LOADB(0, bcA);
    __syncthreads();

    auto body = [&](int t, bf16x8 bcur[2][2], bf16x8 bnext[2][2], int p) {
        if (t + 1 < NKT) STAGE(t + 1, p ^ 1);   // HBM loads in flight first
        #pragma unroll
        for (int kk = 0; kk < 2; ++kk) {
            #pragma unroll
            for (int m = 0; m < 4; ++m) {
                const int R  = m * 16 + fr;
                const int U0 = kk * 8 + fq * 2;
                const float4 a0 = *reinterpret_cast<const float4*>(
                    &As[p][R * 64 + ((U0 ^ (R & 15)) << 2)]);
                const float4 a1 = *reinterpret_cast<const float4*>(
                    &As[p][R * 64 + (((U0 + 1) ^ (R & 15)) << 2)]);
                const bf16x8 af = pack8(a0, a1);
                acc[m][0] = __builtin_amdgcn_mfma_f32_16x16x32_bf16(
                    af, bcur[0][kk], acc[m][0], 0, 0, 0);
                acc[m][1] = __builtin_amdgcn_mfma_f32_16x16x32_bf16(
                    af, bcur[1][kk], acc[m][1], 0, 0, 0);
            }
        }
        if (t + 1 < NKT) LOADB(t + 1, bnext);   // L2 loads drain at barrier
        __syncthreads();                        // A buf p reads done; t+1 ready
    };

    for (int t = 0; t < NKT; t += 2) {
        body(t,     bcA, bcB, 0);
        body(t + 1, bcB, bcA, 1);
    }

    // epilogue: bias + store (C layout: row=(lane>>4)*4+j, col=lane&15)
    #pragma unroll
    for (int n = 0; n < 2; ++n) {
        const int col = wid * 32 + n * 16 + fr;
        #pragma unroll
        for (int m = 0; m < 4; ++m) {
            const long rbase = row0 + m * 16 + fq * 4;
            #pragma unroll
            for (int j = 0; j < 4; ++j)
                xp[(rbase + j) * H_ + col] = acc[m][n][j] + biasr[n];
        }
    }
}

// ---------------------------------------------------------------------------
// Kernel 2 (FROZEN R9, measured ~65 us/pass): 4-wave scan, f16 packed h in
// LDS, v_dot2_f32_f16, shfl_xor(32) k-half combine, lgkm-only barrier,
// 4-deep xp prefetch.
// ---------------------------------------------------------------------------
__global__ __launch_bounds__(256) void scan_kernel(
    const float* __restrict__ xp, const float* __restrict__ Whh,
    const float* __restrict__ Wfc, const float* __restrict__ bfc,
    float* __restrict__ out)
{
    __shared__ __align__(16) unsigned hpk[2][H_ / 2];   // 64 u32 = 128 f16, dbuf

    const int tid  = threadIdx.x;
    const int lane = tid & 63;
    const int w    = tid >> 6;
    const int j    = w * 32 + (lane & 31);
    const int g    = lane >> 5;
    const int b    = blockIdx.x;

    half2v Wh[32];
    {
        const float4* wp = reinterpret_cast<const float4*>(&Whh[(long)j * H_ + g * 64]);
        #pragma unroll
        for (int q = 0; q < 16; ++q) {
            const float4 wv = wp[q];
            half2v p0, p1;
            p0[0] = (_Float16)wv.x; p0[1] = (_Float16)wv.y;
            p1[0] = (_Float16)wv.z; p1[1] = (_Float16)wv.w;
            Wh[2 * q]     = p0;
            Wh[2 * q + 1] = p1;
        }
    }
    if (tid < H_ / 2) hpk[0][tid] = 0u;

    const float* xprow = xp + (long)b * T_ * H_ + j;
    float xa = xprow[0 * H_];
    float xb = xprow[1 * H_];
    float xc = xprow[2 * H_];
    float xd = xprow[3 * H_];
    __syncthreads();

    auto body = [&](int t, float xpv) {
        const uint4* hp = reinterpret_cast<const uint4*>(&hpk[t & 1][g * 32]);
        float a0 = 0.f, a1 = 0.f, a2 = 0.f, a3 = 0.f;
        #pragma unroll
        for (int q = 0; q < 8; ++q) {
            const uint4 u = hp[q];
            a0 = __builtin_amdgcn_fdot2(__builtin_bit_cast(half2v, u.x), Wh[4*q+0], a0, false);
            a1 = __builtin_amdgcn_fdot2(__builtin_bit_cast(half2v, u.y), Wh[4*q+1], a1, false);
            a2 = __builtin_amdgcn_fdot2(__builtin_bit_cast(half2v, u.z), Wh[4*q+2], a2, false);
            a3 = __builtin_amdgcn_fdot2(__builtin_bit_cast(half2v, u.w), Wh[4*q+3], a3, false);
        }
        float part = (a0 + a1) + (a2 + a3);
        part += __shfl_xor(part, 32);
        const float pre = part + xpv;
        const float e = __expf(2.f * pre);      // tanh = 1 - 2/(e^{2x}+1)
        const float h = 1.f - 2.f / (e + 1.f);
        if (g == 0) {
            reinterpret_cast<unsigned short*>(&hpk[(t + 1) & 1][0])[j] =
                __builtin_bit_cast(unsigned short, (_Float16)h);
        }
        LGKM_BARRIER();
    };

    for (int t = 0; t < T_; t += 4) {
        float xu;
        xu = xa; if (t + 4 < T_) xa = xprow[(long)(t + 4) * H_];
        body(t + 0, xu);
        xu = xb; if (t + 5 < T_) xb = xprow[(long)(t + 5) * H_];
        body(t + 1, xu);
        xu = xc; if (t + 6 < T_) xc = xprow[(long)(t + 6) * H_];
        body(t + 2, xu);
        xu = xd; if (t + 7 < T_) xd = xprow[(long)(t + 7) * H_];
        body(t + 3, xu);
    }

    // final FC: h_T is in hpk[0] (t=255 wrote (255+1)&1 = 0)
    if (w == 0) {
        const unsigned u = hpk[0][lane];        // pair h[2l], h[2l+1]
        const half2v hh = __builtin_bit_cast(half2v, u);
        float v = (float)hh[0] * Wfc[2 * lane] + (float)hh[1] * Wfc[2 * lane + 1];
        #pragma unroll
        for (int off = 32; off > 0; off >>= 1) v += __shfl_down(v, off);
        if (lane == 0) out[b] = v + bfc[0];
    }
}

// ---------------------------------------------------------------------------
extern "C" void kernel_launch(void* const* d_in, const int* in_sizes, int n_in,
                              void* d_out, int out_size, void* d_ws, size_t ws_size,
                              hipStream_t stream)
{
    const float* x   = (const float*)d_in[0];
    const float* Wih = (const float*)d_in[1];
    const float* Whh = (const float*)d_in[2];
    const float* bih = (const float*)d_in[3];
    const float* bhh = (const float*)d_in[4];
    const float* Wfc = (const float*)d_in[5];
    const float* bfc = (const float*)d_in[6];
    float* out = (float*)d_out;
    float* xp  = (float*)d_ws;                       // 32 MB scratch
    short* Wb  = (short*)((char*)d_ws + (size_t)B_ * T_ * H_ * sizeof(float));  // bf16 W_ih

    convW<<<dim3((H_ * I_) / (256 * 8)), dim3(256), 0, stream>>>(Wih, Wb);
    proj_mfma<<<dim3((B_ * T_) / BM), dim3(256), 0, stream>>>(x, Wb, bih, bhh, xp);
    scan_kernel<<<dim3(B_), dim3(256), 0, stream>>>(xp, Whh, Wfc, bfc, out);
}